// Round 12
// baseline (118.149 us; speedup 1.0000x reference)
//
#include <hip/hip_runtime.h>
#include <math.h>

constexpr int B = 1024;
constexpr int D = 128;
constexpr int Q = 65536;
constexpr int NPART = 1024;      // 256 N-blocks x 4 wave-cols
#define TEMP_INV 5.0f
#define EPS 1e-12f

typedef __bf16 bf16x8 __attribute__((ext_vector_type(8)));
typedef float  f32x4  __attribute__((ext_vector_type(4)));

__device__ __forceinline__ float wave_reduce_sum(float v) {
    #pragma unroll
    for (int off = 32; off > 0; off >>= 1) v += __shfl_xor(v, off);
    return v;
}

__device__ __forceinline__ unsigned int f2bf(float x) {
    unsigned int u = __float_as_uint(x);
    return (u + 0x7FFFu + ((u >> 16) & 1u)) >> 16;   // RNE, low 16 bits valid
}

// --- K1: small prep: normalize g1/g2 rows -> qnb bf16, pos_sim ------------
// grid = B/2 blocks x 256 threads (2 rows per block)
__global__ __launch_bounds__(256) void k_prep(const float* __restrict__ g1,
                                              const float* __restrict__ g2,
                                              unsigned short* __restrict__ qnb,
                                              float* __restrict__ out_pos,
                                              float* __restrict__ ws_pos) {
    int w2 = threadIdx.x >> 7;          // row within block (0..1)
    int tt = threadIdx.x & 127;         // 0..127 feature dim
    int b  = blockIdx.x * 2 + w2;
    int w  = tt >> 6, lane = tt & 63;
    float x = g1[b * D + tt];
    float y = g2[b * D + tt];
    __shared__ float sx[2][2], sy[2][2], sp[2][2];
    float xs = wave_reduce_sum(x * x);
    float ys = wave_reduce_sum(y * y);
    if (lane == 0) { sx[w2][w] = xs; sy[w2][w] = ys; }
    __syncthreads();
    float ix = 1.0f / fmaxf(sqrtf(sx[w2][0] + sx[w2][1]), EPS);
    float iy = 1.0f / fmaxf(sqrtf(sy[w2][0] + sy[w2][1]), EPS);
    float qv = x * ix;
    float kv = y * iy;
    qnb[b * D + tt] = (unsigned short)f2bf(qv);
    float p = wave_reduce_sum(qv * kv);
    if (lane == 0) sp[w2][w] = p;
    __syncthreads();
    if (tt == 0) {
        float pos = (sp[w2][0] + sp[w2][1]) * TEMP_INV;
        out_pos[b] = pos;
        ws_pos[b]  = pos;
    }
}

// --- K2: fully-fused GEMM: queue-normalize + MFMA + partial sumexp --------
// Grid = 256 blocks (1/CU), 1024 threads. Block owns N-tile of 256 cols:
//   stage 1: normalize its 256 queue rows -> bf16 Bs (K=128 resident)
//   stage 2: 4 M-chunks of 256 rows: stage A from qnb, MFMA (swapped
//            operands -> register-direct stores), fused fixed-ref sumexp.
// No qb intermediate, queue read once from HBM, zero grid tail.
__global__ __launch_bounds__(1024) void k_gemm_fused(const unsigned short* __restrict__ qnb,
                                                     const float* __restrict__ queue,
                                                     float* __restrict__ neg,
                                                     float* __restrict__ psum) {
    __shared__ unsigned short As[256][136];   // 69.6KB (+8 pad)
    __shared__ unsigned short Bs[256][136];   // 69.6KB ; total 139.3KB <= 160KB
    const int t  = threadIdx.x;
    const int bxn = blockIdx.x;    // 0..255 N-tile
    const int C0 = bxn * 256;
    const int wid = t >> 6, lane = t & 63;
    const int wr = wid >> 2, wc = wid & 3;    // 4x4 wave grid
    const int lg = lane >> 4, lc = lane & 15;

    // ---- stage B: normalize queue rows C0..C0+255 into Bs (bf16) ----------
    {
        int row = t >> 2;          // 0..255
        int seg = t & 3;           // 32-float segment of the row
        const f32x4* src = (const f32x4*)(queue + (size_t)(C0 + row) * D + seg * 32);
        f32x4 u[8];
        float ss = 0.0f;
        #pragma unroll
        for (int i = 0; i < 8; ++i) {
            u[i] = __builtin_nontemporal_load(src + i);
            ss += u[i].x * u[i].x + u[i].y * u[i].y + u[i].z * u[i].z + u[i].w * u[i].w;
        }
        ss += __shfl_xor(ss, 1);   // 4 seg-threads per row are consecutive lanes
        ss += __shfl_xor(ss, 2);
        float inv = 1.0f / fmaxf(sqrtf(ss), EPS);
        unsigned short* brow = &Bs[row][seg * 32];
        #pragma unroll
        for (int i = 0; i < 8; i += 2) {
            uint4 wv;
            wv.x = f2bf(u[i].x * inv)     | (f2bf(u[i].y * inv) << 16);
            wv.y = f2bf(u[i].z * inv)     | (f2bf(u[i].w * inv) << 16);
            wv.z = f2bf(u[i + 1].x * inv) | (f2bf(u[i + 1].y * inv) << 16);
            wv.w = f2bf(u[i + 1].z * inv) | (f2bf(u[i + 1].w * inv) << 16);
            *(uint4*)(brow + (i / 2) * 8) = wv;
        }
    }

    // ---- 4 M-chunks of 256 rows ------------------------------------------
    for (int ch = 0; ch < 4; ++ch) {
        __syncthreads();           // As free (prev chunk's reads done); ch0: no-op
        {
            int row = t >> 2;      // 0..255
            int seg = t & 3;       // 32-short segment
            const uint4* asrc = (const uint4*)(qnb + (size_t)(ch * 256 + row) * D + seg * 32);
            unsigned short* arow = &As[row][seg * 32];
            #pragma unroll
            for (int j = 0; j < 4; ++j) *(uint4*)(arow + j * 8) = asrc[j];
        }
        __syncthreads();           // As (+Bs on ch0) visible

        f32x4 acc[4][4];           // [n][m] (swapped-operand output)
        #pragma unroll
        for (int n = 0; n < 4; ++n)
            #pragma unroll
            for (int m = 0; m < 4; ++m)
                #pragma unroll
                for (int r = 0; r < 4; ++r) acc[n][m][r] = 0.0f;

        #pragma unroll
        for (int kk = 0; kk < 128; kk += 32) {
            int ko = kk + lg * 8;
            bf16x8 a[4], b[4];
            #pragma unroll
            for (int m = 0; m < 4; ++m)
                a[m] = *(const bf16x8*)&As[wr * 64 + m * 16 + lc][ko];
            #pragma unroll
            for (int n = 0; n < 4; ++n)
                b[n] = *(const bf16x8*)&Bs[wc * 64 + n * 16 + lc][ko];
            #pragma unroll
            for (int n = 0; n < 4; ++n)
                #pragma unroll
                for (int m = 0; m < 4; ++m)
                    acc[n][m] = __builtin_amdgcn_mfma_f32_16x16x32_bf16(b[n], a[m], acc[n][m], 0, 0, 0);
        }

        // epilogue: register-direct f4 stores + fused fixed-ref sumexp (M=5)
        const int R0 = ch * 256;
        const int slot = bxn * 4 + wc;
        #pragma unroll
        for (int m = 0; m < 4; ++m) {
            const size_t rowBase = (size_t)(R0 + wr * 64 + m * 16 + lc) * Q + C0 + wc * 64;
            float e = 0.0f;
            #pragma unroll
            for (int n = 0; n < 4; ++n) {
                float v0 = acc[n][m][0] * TEMP_INV;
                float v1 = acc[n][m][1] * TEMP_INV;
                float v2 = acc[n][m][2] * TEMP_INV;
                float v3 = acc[n][m][3] * TEMP_INV;
                float4 o = make_float4(v0, v1, v2, v3);
                *(float4*)(neg + rowBase + n * 16 + lg * 4) = o;
                e += __expf(v0 - 5.0f) + __expf(v1 - 5.0f) +
                     __expf(v2 - 5.0f) + __expf(v3 - 5.0f);
            }
            e += __shfl_xor(e, 16);
            e += __shfl_xor(e, 32);
            if (lg == 0) {
                int gr = R0 + wr * 64 + m * 16 + lc;
                psum[(size_t)gr * NPART + slot] = e;
            }
        }
    }
}

// --- K3: reduce 1024 partial sums per row + pos -> atomic mean loss -------
__global__ __launch_bounds__(256) void k_reduce_lse(const float* __restrict__ psum,
                                                    const float* __restrict__ ws_pos,
                                                    float* __restrict__ out) {
    int r = blockIdx.x;
    const float4* pr = (const float4*)(psum + (size_t)r * NPART);
    float4 v = pr[threadIdx.x];        // 256 threads x float4 = 1024 slots
    float s = v.x + v.y + v.z + v.w;
    s = wave_reduce_sum(s);
    __shared__ float sw[4];
    int w = threadIdx.x >> 6, lane = threadIdx.x & 63;
    if (lane == 0) sw[w] = s;
    __syncthreads();
    if (threadIdx.x == 0) {
        float S = sw[0] + sw[1] + sw[2] + sw[3];
        float pos = ws_pos[r];
        S += __expf(pos - 5.0f);
        float loss = (logf(S) + 5.0f) - pos;   // lse - pos
        atomicAdd(out, loss * (1.0f / (float)B));
    }
}

extern "C" void kernel_launch(void* const* d_in, const int* in_sizes, int n_in,
                              void* d_out, int out_size, void* d_ws, size_t ws_size,
                              hipStream_t stream) {
    const float* g1    = (const float*)d_in[0];
    const float* g2    = (const float*)d_in[1];
    const float* queue = (const float*)d_in[2];
    float* out = (float*)d_out;

    float* out_pos = out + 1;          // pos_sim [B]
    float* neg     = out + 1 + B;      // neg_sim [B][Q]

    // ws layout: qnb bf16[B*D] | psum f32[B*NPART] | ws_pos f32[B]
    unsigned short* qnb = (unsigned short*)d_ws;
    float* psum   = (float*)(qnb + (size_t)B * D);
    float* ws_pos = psum + (size_t)B * NPART;

    hipMemsetAsync(out, 0, sizeof(float), stream);   // loss accumulator
    k_prep<<<B / 2, 256, 0, stream>>>(g1, g2, qnb, out_pos, ws_pos);
    k_gemm_fused<<<Q / 256, 1024, 0, stream>>>(qnb, queue, neg, psum);
    k_reduce_lse<<<B, 256, 0, stream>>>(psum, ws_pos, out);
}

// Round 13
// 101.360 us; speedup vs baseline: 1.1656x; 1.1656x over previous
//
#include <hip/hip_runtime.h>
#include <math.h>

constexpr int B = 1024;
constexpr int D = 128;
constexpr int Q = 65536;
constexpr int NPART = 1024;      // 256 N-tiles x 4 wave-cols
#define TEMP_INV 5.0f
#define EPS 1e-12f

typedef __bf16 bf16x8 __attribute__((ext_vector_type(8)));
typedef float  f32x4  __attribute__((ext_vector_type(4)));

__device__ __forceinline__ float wave_reduce_sum(float v) {
    #pragma unroll
    for (int off = 32; off > 0; off >>= 1) v += __shfl_xor(v, off);
    return v;
}

__device__ __forceinline__ unsigned int f2bf(float x) {
    unsigned int u = __float_as_uint(x);
    return (u + 0x7FFFu + ((u >> 16) & 1u)) >> 16;   // RNE, low 16 bits valid
}

// --- K1: fused preprocessing ----------------------------------------------
// blocks [0, 8192):  l2-normalize 8 queue rows -> bf16 qb
// blocks [8192, 8704): normalize 2 g1/g2 rows -> qnb bf16, pos_sim
// last block thread 0 zeroes out[0] (loss accumulator for K3's atomicAdd)
__global__ __launch_bounds__(256) void k_prep(const float* __restrict__ g1,
                                              const float* __restrict__ g2,
                                              const float* __restrict__ queue,
                                              unsigned short* __restrict__ qnb,
                                              unsigned short* __restrict__ qb,
                                              float* __restrict__ out_pos,
                                              float* __restrict__ ws_pos,
                                              float* __restrict__ out_loss) {
    if (blockIdx.x < Q / 8) {
        int half = threadIdx.x >> 5;        // 0..7
        int l    = threadIdx.x & 31;
        int row  = blockIdx.x * 8 + half;
        const f32x4* src = (const f32x4*)(queue + (size_t)row * D);
        f32x4 v = __builtin_nontemporal_load(&src[l]);
        float ss = v.x * v.x + v.y * v.y + v.z * v.z + v.w * v.w;
        #pragma unroll
        for (int off = 16; off > 0; off >>= 1) ss += __shfl_xor(ss, off);
        float inv = 1.0f / fmaxf(sqrtf(ss), EPS);
        uint2 o;
        o.x = f2bf(v.x * inv) | (f2bf(v.y * inv) << 16);
        o.y = f2bf(v.z * inv) | (f2bf(v.w * inv) << 16);
        ((uint2*)(qb + (size_t)row * D))[l] = o;
    } else {
        int idx = blockIdx.x - Q / 8;
        int w2 = threadIdx.x >> 7;          // row within block (0..1)
        int tt = threadIdx.x & 127;         // 0..127 feature dim
        int b  = idx * 2 + w2;
        int w  = tt >> 6, lane = tt & 63;
        float x = g1[b * D + tt];
        float y = g2[b * D + tt];
        __shared__ float sx[2][2], sy[2][2], sp[2][2];
        float xs = wave_reduce_sum(x * x);
        float ys = wave_reduce_sum(y * y);
        if (lane == 0) { sx[w2][w] = xs; sy[w2][w] = ys; }
        __syncthreads();
        float ix = 1.0f / fmaxf(sqrtf(sx[w2][0] + sx[w2][1]), EPS);
        float iy = 1.0f / fmaxf(sqrtf(sy[w2][0] + sy[w2][1]), EPS);
        float qv = x * ix;
        float kv = y * iy;
        qnb[b * D + tt] = (unsigned short)f2bf(qv);
        float p = wave_reduce_sum(qv * kv);
        if (lane == 0) sp[w2][w] = p;
        __syncthreads();
        if (tt == 0) {
            float pos = (sp[w2][0] + sp[w2][1]) * TEMP_INV;
            out_pos[b] = pos;
            ws_pos[b]  = pos;
        }
        if (idx == B / 2 - 1 && threadIdx.x == 0) *out_loss = 0.0f;
    }
}

// --- K2: MFMA GEMM + fused fixed-ref partial sumexp (R11-verbatim) --------
// 256x256 tile, 1024 threads, 4x4 waves; swapped-operand MFMA ->
// register-direct float4 stores, no post-K barriers.
// 1-D grid, by-fastest: 4 consecutive blocks share one qb tile.
__global__ __launch_bounds__(1024) void k_gemm_mfma(const unsigned short* __restrict__ qnb,
                                                    const unsigned short* __restrict__ qb,
                                                    float* __restrict__ neg,
                                                    float* __restrict__ psum) {
    __shared__ unsigned short SM[2][256][72];   // As=SM[0], Bs=SM[1]; 73.7KB
    const int t  = threadIdx.x;
    const int blk = blockIdx.x;
    const int bx = blk >> 2;       // 0..255 over Q (slow)
    const int by = blk & 3;        // 0..3   over B (fast -> qb-tile reuse)
    const int R0 = by * 256, C0 = bx * 256;
    const int wid = t >> 6, lane = t & 63;
    const int wr = wid >> 2, wc = wid & 3;    // 4x4 wave grid
    const int lg = lane >> 4, lc = lane & 15;

    f32x4 acc[4][4];               // [n][m] (transposed output)
    #pragma unroll
    for (int n = 0; n < 4; ++n)
        #pragma unroll
        for (int m = 0; m < 4; ++m)
            #pragma unroll
            for (int r = 0; r < 4; ++r) acc[n][m][r] = 0.0f;

    #pragma unroll
    for (int s = 0; s < 2; ++s) {
        if (s) __syncthreads();
        const int ks = s * 64;
        #pragma unroll
        for (int p = 0; p < 2; ++p) {
            int c   = t + 1024 * p;
            int row = c >> 3;          // 0..255
            int off = (c & 7) * 8;     // bf16 col, 0..56
            uint4 va = *(const uint4*)(qnb + (size_t)(R0 + row) * D + ks + off);
            uint4 vb = *(const uint4*)(qb  + (size_t)(C0 + row) * D + ks + off);
            *(uint4*)&SM[0][row][off] = va;
            *(uint4*)&SM[1][row][off] = vb;
        }
        __syncthreads();
        #pragma unroll
        for (int kk = 0; kk < 64; kk += 32) {
            int ko = kk + lg * 8;
            bf16x8 a[4], b[4];
            #pragma unroll
            for (int m = 0; m < 4; ++m)
                a[m] = *(const bf16x8*)&SM[0][wr * 64 + m * 16 + lc][ko];
            #pragma unroll
            for (int n = 0; n < 4; ++n)
                b[n] = *(const bf16x8*)&SM[1][wc * 64 + n * 16 + lc][ko];
            #pragma unroll
            for (int n = 0; n < 4; ++n)
                #pragma unroll
                for (int m = 0; m < 4; ++m)
                    acc[n][m] = __builtin_amdgcn_mfma_f32_16x16x32_bf16(b[n], a[m], acc[n][m], 0, 0, 0);
        }
    }

    // epilogue: register-direct f4 stores + fused fixed-ref sumexp (M=5)
    const int slot = bx * 4 + wc;
    #pragma unroll
    for (int m = 0; m < 4; ++m) {
        const size_t rowBase = (size_t)(R0 + wr * 64 + m * 16 + lc) * Q + C0 + wc * 64;
        float e = 0.0f;
        #pragma unroll
        for (int n = 0; n < 4; ++n) {
            float v0 = acc[n][m][0] * TEMP_INV;
            float v1 = acc[n][m][1] * TEMP_INV;
            float v2 = acc[n][m][2] * TEMP_INV;
            float v3 = acc[n][m][3] * TEMP_INV;
            float4 o = make_float4(v0, v1, v2, v3);
            *(float4*)(neg + rowBase + n * 16 + lg * 4) = o;
            e += __expf(v0 - 5.0f) + __expf(v1 - 5.0f) +
                 __expf(v2 - 5.0f) + __expf(v3 - 5.0f);
        }
        e += __shfl_xor(e, 16);
        e += __shfl_xor(e, 32);
        if (lg == 0) {
            int gr = R0 + wr * 64 + m * 16 + lc;
            psum[(size_t)gr * NPART + slot] = e;
        }
    }
}

// --- K3: per-row LSE (deterministic) + atomic mean loss -------------------
__global__ __launch_bounds__(256) void k_reduce_lse(const float* __restrict__ psum,
                                                    const float* __restrict__ ws_pos,
                                                    float* __restrict__ out) {
    int r = blockIdx.x;
    const float4* pr = (const float4*)(psum + (size_t)r * NPART);
    float4 v = pr[threadIdx.x];        // 256 threads x float4 = 1024 slots
    float s = v.x + v.y + v.z + v.w;
    s = wave_reduce_sum(s);
    __shared__ float sw[4];
    int w = threadIdx.x >> 6, lane = threadIdx.x & 63;
    if (lane == 0) sw[w] = s;
    __syncthreads();
    if (threadIdx.x == 0) {
        float S = sw[0] + sw[1] + sw[2] + sw[3];
        float pos = ws_pos[r];
        S += __expf(pos - 5.0f);
        float loss = (logf(S) + 5.0f) - pos;   // lse - pos
        atomicAdd(out, loss * (1.0f / (float)B));
    }
}

extern "C" void kernel_launch(void* const* d_in, const int* in_sizes, int n_in,
                              void* d_out, int out_size, void* d_ws, size_t ws_size,
                              hipStream_t stream) {
    const float* g1    = (const float*)d_in[0];
    const float* g2    = (const float*)d_in[1];
    const float* queue = (const float*)d_in[2];
    float* out = (float*)d_out;

    float* out_pos = out + 1;          // pos_sim [B]
    float* neg     = out + 1 + B;      // neg_sim [B][Q]

    // ws layout: qnb bf16[B*D] | qb bf16[Q*D] | psum f32[B*NPART] | ws_pos f32[B]
    unsigned short* qnb = (unsigned short*)d_ws;
    unsigned short* qb  = qnb + (size_t)B * D;
    float* psum   = (float*)(qb + (size_t)Q * D);
    float* ws_pos = psum + (size_t)B * NPART;

    k_prep<<<Q / 8 + B / 2, 256, 0, stream>>>(g1, g2, queue, qnb, qb, out_pos, ws_pos, out);
    k_gemm_mfma<<<(Q / 256) * (B / 256), 1024, 0, stream>>>(qnb, qb, neg, psum);
    k_reduce_lse<<<B, 256, 0, stream>>>(psum, ws_pos, out);
}

// Round 14
// 91.439 us; speedup vs baseline: 1.2921x; 1.1085x over previous
//
#include <hip/hip_runtime.h>
#include <math.h>

constexpr int B = 1024;
constexpr int D = 128;
constexpr int Q = 65536;
constexpr int NPART = 1024;      // 256 N-tiles x 4 wave-cols
#define TEMP_INV 5.0f
#define EPS 1e-12f

typedef __bf16 bf16x8 __attribute__((ext_vector_type(8)));
typedef float  f32x4  __attribute__((ext_vector_type(4)));

__device__ __forceinline__ float wave_reduce_sum(float v) {
    #pragma unroll
    for (int off = 32; off > 0; off >>= 1) v += __shfl_xor(v, off);
    return v;
}

__device__ __forceinline__ unsigned short f2bf(float x) {
    unsigned int u = __float_as_uint(x);
    unsigned int r = (u + 0x7FFFu + ((u >> 16) & 1u)) >> 16;   // RNE
    return (unsigned short)r;
}

// --- K1: fused preprocessing ----------------------------------------------
// blocks [0, 8192):  l2-normalize 8 queue rows -> bf16 qb
// blocks [8192, 8704): normalize 2 g1/g2 rows -> qnb bf16, pos_sim
__global__ __launch_bounds__(256) void k_prep(const float* __restrict__ g1,
                                              const float* __restrict__ g2,
                                              const float* __restrict__ queue,
                                              unsigned short* __restrict__ qnb,
                                              unsigned short* __restrict__ qb,
                                              float* __restrict__ out_pos,
                                              float* __restrict__ ws_pos) {
    if (blockIdx.x < Q / 8) {
        int half = threadIdx.x >> 5;        // 0..7
        int l    = threadIdx.x & 31;
        int row  = blockIdx.x * 8 + half;
        const f32x4* src = (const f32x4*)(queue + (size_t)row * D);
        f32x4 v = __builtin_nontemporal_load(&src[l]);
        float ss = v.x * v.x + v.y * v.y + v.z * v.z + v.w * v.w;
        #pragma unroll
        for (int off = 16; off > 0; off >>= 1) ss += __shfl_xor(ss, off);
        float inv = 1.0f / fmaxf(sqrtf(ss), EPS);
        uint2 o;
        o.x = (unsigned int)f2bf(v.x * inv) | ((unsigned int)f2bf(v.y * inv) << 16);
        o.y = (unsigned int)f2bf(v.z * inv) | ((unsigned int)f2bf(v.w * inv) << 16);
        ((uint2*)(qb + (size_t)row * D))[l] = o;
    } else {
        int idx = blockIdx.x - Q / 8;
        int w2 = threadIdx.x >> 7;          // row within block (0..1)
        int tt = threadIdx.x & 127;         // 0..127 feature dim
        int b  = idx * 2 + w2;
        int w  = tt >> 6, lane = tt & 63;
        float x = g1[b * D + tt];
        float y = g2[b * D + tt];
        __shared__ float sx[2][2], sy[2][2], sp[2][2];
        float xs = wave_reduce_sum(x * x);
        float ys = wave_reduce_sum(y * y);
        if (lane == 0) { sx[w2][w] = xs; sy[w2][w] = ys; }
        __syncthreads();
        float ix = 1.0f / fmaxf(sqrtf(sx[w2][0] + sx[w2][1]), EPS);
        float iy = 1.0f / fmaxf(sqrtf(sy[w2][0] + sy[w2][1]), EPS);
        float qv = x * ix;
        float kv = y * iy;
        qnb[b * D + tt] = f2bf(qv);
        float p = wave_reduce_sum(qv * kv);
        if (lane == 0) sp[w2][w] = p;
        __syncthreads();
        if (tt == 0) {
            float pos = (sp[w2][0] + sp[w2][1]) * TEMP_INV;
            out_pos[b] = pos;
            ws_pos[b]  = pos;
        }
    }
}

// --- K2: MFMA GEMM + fused fixed-ref partial sumexp -----------------------
// 256x256 tile, 1024 threads, 4x4 waves (each wave 64x64 output).
// SWAPPED-OPERAND MFMA: acc[n][m] = mfma(b[n], a[m]) -> output row=j, col=b;
// each lane's 4 regs are 4 consecutive j -> direct float4 stores from regs,
// no LDS transpose, no post-K barriers.
// 1-D grid, by-fastest: 4 consecutive blocks share one qb tile.
__global__ __launch_bounds__(1024) void k_gemm_mfma(const unsigned short* __restrict__ qnb,
                                                    const unsigned short* __restrict__ qb,
                                                    float* __restrict__ neg,
                                                    float* __restrict__ psum) {
    __shared__ unsigned short SM[2][256][72];   // As=SM[0], Bs=SM[1]; 73.7KB
    const int t  = threadIdx.x;
    const int blk = blockIdx.x;
    const int bx = blk >> 2;       // 0..255 over Q (slow)
    const int by = blk & 3;        // 0..3   over B (fast -> qb-tile reuse)
    const int R0 = by * 256, C0 = bx * 256;
    const int wid = t >> 6, lane = t & 63;
    const int wr = wid >> 2, wc = wid & 3;    // 4x4 wave grid
    const int lg = lane >> 4, lc = lane & 15;

    f32x4 acc[4][4];               // [n][m] (transposed output)
    #pragma unroll
    for (int n = 0; n < 4; ++n)
        #pragma unroll
        for (int m = 0; m < 4; ++m)
            #pragma unroll
            for (int r = 0; r < 4; ++r) acc[n][m][r] = 0.0f;

    #pragma unroll
    for (int s = 0; s < 2; ++s) {
        if (s) __syncthreads();
        const int ks = s * 64;
        #pragma unroll
        for (int p = 0; p < 2; ++p) {
            int c   = t + 1024 * p;
            int row = c >> 3;          // 0..255
            int off = (c & 7) * 8;     // bf16 col, 0..56
            uint4 va = *(const uint4*)(qnb + (size_t)(R0 + row) * D + ks + off);
            uint4 vb = *(const uint4*)(qb  + (size_t)(C0 + row) * D + ks + off);
            *(uint4*)&SM[0][row][off] = va;
            *(uint4*)&SM[1][row][off] = vb;
        }
        __syncthreads();
        #pragma unroll
        for (int kk = 0; kk < 64; kk += 32) {
            int ko = kk + lg * 8;
            bf16x8 a[4], b[4];
            #pragma unroll
            for (int m = 0; m < 4; ++m)
                a[m] = *(const bf16x8*)&SM[0][wr * 64 + m * 16 + lc][ko];
            #pragma unroll
            for (int n = 0; n < 4; ++n)
                b[n] = *(const bf16x8*)&SM[1][wc * 64 + n * 16 + lc][ko];
            #pragma unroll
            for (int n = 0; n < 4; ++n)
                #pragma unroll
                for (int m = 0; m < 4; ++m)
                    acc[n][m] = __builtin_amdgcn_mfma_f32_16x16x32_bf16(b[n], a[m], acc[n][m], 0, 0, 0);
        }
    }

    // ---- epilogue: direct register->global float4 stores + fused fixed-ref
    //      sumexp (logits in [-5,5] -> M=5). No barriers, no LDS.
    //      Lane (lg,lc), frag (n,m): row b = R0+wr*64+m*16+lc,
    //      cols j = C0+wc*64+n*16+lg*4 .. +3 (4 consecutive -> float4).
    const int slot = bx * 4 + wc;
    #pragma unroll
    for (int m = 0; m < 4; ++m) {
        const size_t rowBase = (size_t)(R0 + wr * 64 + m * 16 + lc) * Q + C0 + wc * 64;
        float e = 0.0f;
        #pragma unroll
        for (int n = 0; n < 4; ++n) {
            float v0 = acc[n][m][0] * TEMP_INV;
            float v1 = acc[n][m][1] * TEMP_INV;
            float v2 = acc[n][m][2] * TEMP_INV;
            float v3 = acc[n][m][3] * TEMP_INV;
            float4 o = make_float4(v0, v1, v2, v3);
            *(float4*)(neg + rowBase + n * 16 + lg * 4) = o;
            e += __expf(v0 - 5.0f) + __expf(v1 - 5.0f) +
                 __expf(v2 - 5.0f) + __expf(v3 - 5.0f);
        }
        // reduce over the 4 lg-groups holding this row's 64 j values
        e += __shfl_xor(e, 16);
        e += __shfl_xor(e, 32);
        if (lg == 0) {
            int gr = R0 + wr * 64 + m * 16 + lc;
            psum[(size_t)gr * NPART + slot] = e;
        }
    }
}

// --- K3: reduce 1024 partial sums per row + pos -> loss_b -----------------
__global__ __launch_bounds__(256) void k_reduce_lse(const float* __restrict__ psum,
                                                    const float* __restrict__ ws_pos,
                                                    float* __restrict__ loss_b) {
    int r = blockIdx.x;
    const float4* pr = (const float4*)(psum + (size_t)r * NPART);
    float4 v = pr[threadIdx.x];        // 256 threads x float4 = 1024 slots
    float s = v.x + v.y + v.z + v.w;
    s = wave_reduce_sum(s);
    __shared__ float sw[4];
    int w = threadIdx.x >> 6, lane = threadIdx.x & 63;
    if (lane == 0) sw[w] = s;
    __syncthreads();
    if (threadIdx.x == 0) {
        float S = sw[0] + sw[1] + sw[2] + sw[3];
        float pos = ws_pos[r];
        S += __expf(pos - 5.0f);
        loss_b[r] = (logf(S) + 5.0f) - pos;   // lse - pos
    }
}

// --- K4: mean of loss_b -> out[0] -----------------------------------------
__global__ void k_loss_mean(const float* __restrict__ loss_b, float* __restrict__ out) {
    float s = 0.0f;
    for (int i = threadIdx.x; i < B; i += 256) s += loss_b[i];
    s = wave_reduce_sum(s);
    __shared__ float sw[4];
    int w = threadIdx.x >> 6, lane = threadIdx.x & 63;
    if (lane == 0) sw[w] = s;
    __syncthreads();
    if (threadIdx.x == 0) out[0] = (sw[0] + sw[1] + sw[2] + sw[3]) / (float)B;
}

extern "C" void kernel_launch(void* const* d_in, const int* in_sizes, int n_in,
                              void* d_out, int out_size, void* d_ws, size_t ws_size,
                              hipStream_t stream) {
    const float* g1    = (const float*)d_in[0];
    const float* g2    = (const float*)d_in[1];
    const float* queue = (const float*)d_in[2];
    float* out = (float*)d_out;

    float* out_pos = out + 1;          // pos_sim [B]
    float* neg     = out + 1 + B;      // neg_sim [B][Q]

    // ws layout: qnb bf16[B*D] | qb bf16[Q*D] | psum f32[B*NPART]
    //            | ws_pos f32[B] | loss_b f32[B]
    unsigned short* qnb = (unsigned short*)d_ws;
    unsigned short* qb  = qnb + (size_t)B * D;
    float* psum   = (float*)(qb + (size_t)Q * D);
    float* ws_pos = psum + (size_t)B * NPART;
    float* loss_b = ws_pos + B;

    k_prep<<<Q / 8 + B / 2, 256, 0, stream>>>(g1, g2, queue, qnb, qb, out_pos, ws_pos);
    k_gemm_mfma<<<(Q / 256) * (B / 256), 1024, 0, stream>>>(qnb, qb, neg, psum);
    k_reduce_lse<<<B, 256, 0, stream>>>(psum, ws_pos, loss_b);
    k_loss_mean<<<1, 256, 0, stream>>>(loss_b, out);
}

// Round 15
// 88.949 us; speedup vs baseline: 1.3283x; 1.0280x over previous
//
#include <hip/hip_runtime.h>
#include <math.h>

constexpr int B = 1024;
constexpr int D = 128;
constexpr int Q = 65536;
constexpr int NPART = 1024;      // 256 N-tiles x 4 wave-cols
#define TEMP_INV 5.0f
#define EPS 1e-12f

typedef __bf16 bf16x8 __attribute__((ext_vector_type(8)));
typedef float  f32x4  __attribute__((ext_vector_type(4)));

__device__ __forceinline__ float wave_reduce_sum(float v) {
    #pragma unroll
    for (int off = 32; off > 0; off >>= 1) v += __shfl_xor(v, off);
    return v;
}

__device__ __forceinline__ unsigned short f2bf(float x) {
    unsigned int u = __float_as_uint(x);
    unsigned int r = (u + 0x7FFFu + ((u >> 16) & 1u)) >> 16;   // RNE
    return (unsigned short)r;
}

// --- K1: fused preprocessing ----------------------------------------------
// blocks [0, 8192):  l2-normalize 8 queue rows -> bf16 qb
// blocks [8192, 8704): normalize 2 g1/g2 rows -> qnb bf16, pos_sim
__global__ __launch_bounds__(256) void k_prep(const float* __restrict__ g1,
                                              const float* __restrict__ g2,
                                              const float* __restrict__ queue,
                                              unsigned short* __restrict__ qnb,
                                              unsigned short* __restrict__ qb,
                                              float* __restrict__ out_pos,
                                              float* __restrict__ ws_pos) {
    if (blockIdx.x < Q / 8) {
        int half = threadIdx.x >> 5;        // 0..7
        int l    = threadIdx.x & 31;
        int row  = blockIdx.x * 8 + half;
        const f32x4* src = (const f32x4*)(queue + (size_t)row * D);
        f32x4 v = __builtin_nontemporal_load(&src[l]);
        float ss = v.x * v.x + v.y * v.y + v.z * v.z + v.w * v.w;
        #pragma unroll
        for (int off = 16; off > 0; off >>= 1) ss += __shfl_xor(ss, off);
        float inv = 1.0f / fmaxf(sqrtf(ss), EPS);
        uint2 o;
        o.x = (unsigned int)f2bf(v.x * inv) | ((unsigned int)f2bf(v.y * inv) << 16);
        o.y = (unsigned int)f2bf(v.z * inv) | ((unsigned int)f2bf(v.w * inv) << 16);
        ((uint2*)(qb + (size_t)row * D))[l] = o;
    } else {
        int idx = blockIdx.x - Q / 8;
        int w2 = threadIdx.x >> 7;          // row within block (0..1)
        int tt = threadIdx.x & 127;         // 0..127 feature dim
        int b  = idx * 2 + w2;
        int w  = tt >> 6, lane = tt & 63;
        float x = g1[b * D + tt];
        float y = g2[b * D + tt];
        __shared__ float sx[2][2], sy[2][2], sp[2][2];
        float xs = wave_reduce_sum(x * x);
        float ys = wave_reduce_sum(y * y);
        if (lane == 0) { sx[w2][w] = xs; sy[w2][w] = ys; }
        __syncthreads();
        float ix = 1.0f / fmaxf(sqrtf(sx[w2][0] + sx[w2][1]), EPS);
        float iy = 1.0f / fmaxf(sqrtf(sy[w2][0] + sy[w2][1]), EPS);
        float qv = x * ix;
        float kv = y * iy;
        qnb[b * D + tt] = f2bf(qv);
        float p = wave_reduce_sum(qv * kv);
        if (lane == 0) sp[w2][w] = p;
        __syncthreads();
        if (tt == 0) {
            float pos = (sp[w2][0] + sp[w2][1]) * TEMP_INV;
            out_pos[b] = pos;
            ws_pos[b]  = pos;
        }
    }
}

// --- K2: MFMA GEMM + fused fixed-ref partial sumexp -----------------------
// 256x256 tile, 1024 threads, 4x4 waves; swapped-operand MFMA ->
// register-direct float4 stores, no post-K barriers.
// XCD-aware swizzle: dispatch round-robins XCD = blk&7; give each XCD a
// contiguous bx range and keep the 4 by-blocks of one bx consecutive on
// the SAME XCD -> qb tile: 1 L3 fetch + 3 same-XCD L2 hits.
__global__ __launch_bounds__(1024) void k_gemm_mfma(const unsigned short* __restrict__ qnb,
                                                    const unsigned short* __restrict__ qb,
                                                    float* __restrict__ neg,
                                                    float* __restrict__ psum) {
    __shared__ unsigned short SM[2][256][72];   // As=SM[0], Bs=SM[1]; 73.7KB
    const int t  = threadIdx.x;
    const int blk = blockIdx.x;
    const int xcd = blk & 7;       // dispatch XCD (round-robin)
    const int i   = blk >> 3;      // 0..127 local index within XCD
    const int bx  = xcd * 32 + (i >> 2);   // 0..255 over Q, contiguous per XCD
    const int by  = i & 3;                  // 0..3 over B (fast -> qb reuse in-XCD)
    const int R0 = by * 256, C0 = bx * 256;
    const int wid = t >> 6, lane = t & 63;
    const int wr = wid >> 2, wc = wid & 3;    // 4x4 wave grid
    const int lg = lane >> 4, lc = lane & 15;

    f32x4 acc[4][4];               // [n][m] (transposed output)
    #pragma unroll
    for (int n = 0; n < 4; ++n)
        #pragma unroll
        for (int m = 0; m < 4; ++m)
            #pragma unroll
            for (int r = 0; r < 4; ++r) acc[n][m][r] = 0.0f;

    #pragma unroll
    for (int s = 0; s < 2; ++s) {
        if (s) __syncthreads();
        const int ks = s * 64;
        #pragma unroll
        for (int p = 0; p < 2; ++p) {
            int c   = t + 1024 * p;
            int row = c >> 3;          // 0..255
            int off = (c & 7) * 8;     // bf16 col, 0..56
            uint4 va = *(const uint4*)(qnb + (size_t)(R0 + row) * D + ks + off);
            uint4 vb = *(const uint4*)(qb  + (size_t)(C0 + row) * D + ks + off);
            *(uint4*)&SM[0][row][off] = va;
            *(uint4*)&SM[1][row][off] = vb;
        }
        __syncthreads();
        #pragma unroll
        for (int kk = 0; kk < 64; kk += 32) {
            int ko = kk + lg * 8;
            bf16x8 a[4], b[4];
            #pragma unroll
            for (int m = 0; m < 4; ++m)
                a[m] = *(const bf16x8*)&SM[0][wr * 64 + m * 16 + lc][ko];
            #pragma unroll
            for (int n = 0; n < 4; ++n)
                b[n] = *(const bf16x8*)&SM[1][wc * 64 + n * 16 + lc][ko];
            #pragma unroll
            for (int n = 0; n < 4; ++n)
                #pragma unroll
                for (int m = 0; m < 4; ++m)
                    acc[n][m] = __builtin_amdgcn_mfma_f32_16x16x32_bf16(b[n], a[m], acc[n][m], 0, 0, 0);
        }
    }

    // ---- epilogue: direct register->global float4 stores + fused fixed-ref
    //      sumexp (logits in [-5,5] -> M=5). No barriers, no LDS.
    const int slot = bx * 4 + wc;
    #pragma unroll
    for (int m = 0; m < 4; ++m) {
        const size_t rowBase = (size_t)(R0 + wr * 64 + m * 16 + lc) * Q + C0 + wc * 64;
        float e = 0.0f;
        #pragma unroll
        for (int n = 0; n < 4; ++n) {
            float v0 = acc[n][m][0] * TEMP_INV;
            float v1 = acc[n][m][1] * TEMP_INV;
            float v2 = acc[n][m][2] * TEMP_INV;
            float v3 = acc[n][m][3] * TEMP_INV;
            float4 o = make_float4(v0, v1, v2, v3);
            *(float4*)(neg + rowBase + n * 16 + lg * 4) = o;
            e += __expf(v0 - 5.0f) + __expf(v1 - 5.0f) +
                 __expf(v2 - 5.0f) + __expf(v3 - 5.0f);
        }
        e += __shfl_xor(e, 16);
        e += __shfl_xor(e, 32);
        if (lg == 0) {
            int gr = R0 + wr * 64 + m * 16 + lc;
            psum[(size_t)gr * NPART + slot] = e;
        }
    }
}

// --- K3: reduce 1024 partial sums per row + pos -> loss_b -----------------
__global__ __launch_bounds__(256) void k_reduce_lse(const float* __restrict__ psum,
                                                    const float* __restrict__ ws_pos,
                                                    float* __restrict__ loss_b) {
    int r = blockIdx.x;
    const float4* pr = (const float4*)(psum + (size_t)r * NPART);
    float4 v = pr[threadIdx.x];        // 256 threads x float4 = 1024 slots
    float s = v.x + v.y + v.z + v.w;
    s = wave_reduce_sum(s);
    __shared__ float sw[4];
    int w = threadIdx.x >> 6, lane = threadIdx.x & 63;
    if (lane == 0) sw[w] = s;
    __syncthreads();
    if (threadIdx.x == 0) {
        float S = sw[0] + sw[1] + sw[2] + sw[3];
        float pos = ws_pos[r];
        S += __expf(pos - 5.0f);
        loss_b[r] = (logf(S) + 5.0f) - pos;   // lse - pos
    }
}

// --- K4: mean of loss_b -> out[0] -----------------------------------------
__global__ void k_loss_mean(const float* __restrict__ loss_b, float* __restrict__ out) {
    float s = 0.0f;
    for (int i = threadIdx.x; i < B; i += 256) s += loss_b[i];
    s = wave_reduce_sum(s);
    __shared__ float sw[4];
    int w = threadIdx.x >> 6, lane = threadIdx.x & 63;
    if (lane == 0) sw[w] = s;
    __syncthreads();
    if (threadIdx.x == 0) out[0] = (sw[0] + sw[1] + sw[2] + sw[3]) / (float)B;
}

extern "C" void kernel_launch(void* const* d_in, const int* in_sizes, int n_in,
                              void* d_out, int out_size, void* d_ws, size_t ws_size,
                              hipStream_t stream) {
    const float* g1    = (const float*)d_in[0];
    const float* g2    = (const float*)d_in[1];
    const float* queue = (const float*)d_in[2];
    float* out = (float*)d_out;

    float* out_pos = out + 1;          // pos_sim [B]
    float* neg     = out + 1 + B;      // neg_sim [B][Q]

    // ws layout: qnb bf16[B*D] | qb bf16[Q*D] | psum f32[B*NPART]
    //            | ws_pos f32[B] | loss_b f32[B]
    unsigned short* qnb = (unsigned short*)d_ws;
    unsigned short* qb  = qnb + (size_t)B * D;
    float* psum   = (float*)(qb + (size_t)Q * D);
    float* ws_pos = psum + (size_t)B * NPART;
    float* loss_b = ws_pos + B;

    k_prep<<<Q / 8 + B / 2, 256, 0, stream>>>(g1, g2, queue, qnb, qb, out_pos, ws_pos);
    k_gemm_mfma<<<(Q / 256) * (B / 256), 1024, 0, stream>>>(qnb, qb, neg, psum);
    k_reduce_lse<<<B, 256, 0, stream>>>(psum, ws_pos, loss_b);
    k_loss_mean<<<1, 256, 0, stream>>>(loss_b, out);
}